// Round 4
// baseline (272.765 us; speedup 1.0000x reference)
//
#include <hip/hip_runtime.h>
#include <hip/hip_bf16.h>

typedef unsigned short u16;
typedef unsigned int   u32;
typedef __attribute__((ext_vector_type(8))) __bf16 bf16x8;
typedef __attribute__((ext_vector_type(2))) __bf16 bf16x2;
typedef __attribute__((ext_vector_type(8))) u16    ushort8v;
typedef __attribute__((ext_vector_type(2))) float  f32x2;
typedef __attribute__((ext_vector_type(4))) float  floatx4;

#define EMBED 1024
#define SEQ   2048
#define BATCH 4
#define NH    16
#define DKH   64
#define BHN   (BATCH*NH)              // 64
#define ZSTRIDE ((size_t)BHN*SEQ*DKH) // elements per Q/K/V plane

// ---- fp32 -> bf16 RTNE ----
__device__ __forceinline__ u16 f2bf(float f){
  union { float f; unsigned u; } v; v.f = f;
  unsigned r = (v.u + 0x7FFFu + ((v.u >> 16) & 1u)) >> 16;
  return (u16)r;
}
// packed pair via v_cvt_pk_bf16_f32
__device__ __forceinline__ u32 pk2(float a, float b){
  f32x2 v = {a, b};
  return __builtin_bit_cast(u32, __builtin_convertvector(v, bf16x2));
}

__device__ __forceinline__ bf16x8 ld_frag(const u16* p){
  return __builtin_bit_cast(bf16x8, *(const ushort8v*)p);
}

__device__ __forceinline__ floatx4 mfma16(bf16x8 a, bf16x8 b, floatx4 c){
  return __builtin_amdgcn_mfma_f32_16x16x32_bf16(a, b, c, 0, 0, 0);
}

// async global->LDS, 16B per lane; LDS dst must be uniform_base + lane*16
__device__ __forceinline__ void gl_lds16(const u16* g, u16* l){
  __builtin_amdgcn_global_load_lds((const __attribute__((address_space(1))) void*)g,
                                   (__attribute__((address_space(3))) void*)l,
                                   16, 0, 0);
}

// =================== fused cast kernel ===================
__global__ __launch_bounds__(256) void cvt_all(const float* __restrict__ x,
    const float* __restrict__ wq, const float* __restrict__ wk,
    const float* __restrict__ wv, const float* __restrict__ wo,
    u16* __restrict__ Xb, u16* __restrict__ Wqb, u16* __restrict__ Wkb,
    u16* __restrict__ Wvb, u16* __restrict__ Wob){
  int b = blockIdx.x;
  const float* src; u16* dst; int i;
  if (b < 8192){ src = x; dst = Xb; i = b*256 + threadIdx.x; }
  else {
    int k = (b - 8192) >> 10, r = (b - 8192) & 1023;
    src = (k==0) ? wq : (k==1) ? wk : (k==2) ? wv : wo;
    dst = (k==0) ? Wqb : (k==1) ? Wkb : (k==2) ? Wvb : Wob;
    i = r*256 + threadIdx.x;
  }
  float4 v = ((const float4*)src)[i];
  ushort4 o;
  o.x = f2bf(v.x); o.y = f2bf(v.y); o.z = f2bf(v.z); o.w = f2bf(v.w);
  ((ushort4*)dst)[i] = o;
}

// ========== GEMM core (for gemm_out): double-buffered DMA, ONE barrier/kt ======
__device__ __forceinline__ void gemm_core_db(const u16* Abase, const u16* Bbase,
                                             u16* As, u16* Bs, floatx4 acc[4][4]){
  const int tid  = threadIdx.x;
  const int lane = tid & 63, w = tid >> 6;
  const int lm   = lane & 15, quad = lane >> 4;
  const int wm   = (w & 1) * 64, wn = (w >> 1) * 64;
  const int row0 = tid >> 2, kc = tid & 3;
  const int row1 = (256 + tid) >> 2;

  #pragma unroll
  for (int mi = 0; mi < 4; ++mi)
    #pragma unroll
    for (int ni = 0; ni < 4; ++ni)
      acc[mi][ni] = (floatx4){0.f, 0.f, 0.f, 0.f};

  gl_lds16(Abase + (size_t)row0*EMBED + kc*8, As + tid*8);
  gl_lds16(Bbase + (size_t)row0*EMBED + kc*8, Bs + tid*8);
  gl_lds16(Abase + (size_t)row1*EMBED + kc*8, As + (256 + tid)*8);
  gl_lds16(Bbase + (size_t)row1*EMBED + kc*8, Bs + (256 + tid)*8);

  for (int kt = 0; kt < EMBED/32; ++kt){
    const int cur = kt & 1;
    __syncthreads();
    if (kt + 1 < EMBED/32){
      const int k0 = (kt + 1) * 32;
      u16* Ad = As + (cur^1)*128*32;
      u16* Bd = Bs + (cur^1)*128*32;
      gl_lds16(Abase + (size_t)row0*EMBED + k0 + kc*8, Ad + tid*8);
      gl_lds16(Bbase + (size_t)row0*EMBED + k0 + kc*8, Bd + tid*8);
      gl_lds16(Abase + (size_t)row1*EMBED + k0 + kc*8, Ad + (256 + tid)*8);
      gl_lds16(Bbase + (size_t)row1*EMBED + k0 + kc*8, Bd + (256 + tid)*8);
    }
    const u16* Ac = As + cur*128*32;
    const u16* Bc = Bs + cur*128*32;
    bf16x8 af[4], bf[4];
    #pragma unroll
    for (int mi = 0; mi < 4; ++mi)
      af[mi] = ld_frag(&Ac[(wm + mi*16 + lm)*32 + quad*8]);
    #pragma unroll
    for (int ni = 0; ni < 4; ++ni)
      bf[ni] = ld_frag(&Bc[(wn + ni*16 + lm)*32 + quad*8]);
    #pragma unroll
    for (int mi = 0; mi < 4; ++mi)
      #pragma unroll
      for (int ni = 0; ni < 4; ++ni)
        acc[mi][ni] = mfma16(af[mi], bf[ni], acc[mi][ni]);
  }
}

// ============== fused QKV projection v2: occupancy-balanced ====================
// R3 diagnosis: acc[3][4][4] = 192 AGPRs + 112 arch = ~304/512 regs -> 1
// wave/SIMD (CSV VGPR_Count hides AGPRs). Fix: tile 128m x 64n x 3z per block,
// 4 waves, wave owns 64x32 per z -> acc[3][4][2] = 96 acc + ~60 arch ≈ 155
// -> 3 waves/SIMD. LDS 40 KB (A 16K + 3xB 8K dbuf) -> 3 blocks/CU resident;
// cross-block overlap hides barrier drains. grid (64,16): linear id %8 = x%8
// -> all n-blocks of an m-tile share the XCD (X tile L2-resident).
// 24 MFMA/wave/kt against one barrier; 5 DMA issues/thread/kt.
#define QSCALE 0.1803368801111204f   // 0.125 * log2(e)
__global__ __launch_bounds__(256, 3) void gemm_qkv(const u16* __restrict__ X,
    const u16* __restrict__ Wq, const u16* __restrict__ Wk, const u16* __restrict__ Wv,
    u16* __restrict__ QKV){
  __shared__ __attribute__((aligned(16))) u16 As[2*128*32];      // 16 KB
  __shared__ __attribute__((aligned(16))) u16 Bs[3][2*64*32];    // 24 KB

  const int tid = threadIdx.x, lane = tid & 63, w = tid >> 6;
  const int lm = lane & 15, quad = lane >> 4;
  const int wm = (w & 1) * 64, wn = (w >> 1) * 32;
  const int m0 = blockIdx.x * 128, n0 = blockIdx.y * 64;
  const int row = tid >> 2, kc = tid & 3;   // A rows 0..63 (+64 for 2nd), B rows 0..63

  const u16* A0 = X  + (size_t)(m0 + row)*EMBED + kc*8;   // +64*EMBED for 2nd half
  const u16* B0[3] = {
    Wq + (size_t)(n0 + row)*EMBED + kc*8,
    Wk + (size_t)(n0 + row)*EMBED + kc*8,
    Wv + (size_t)(n0 + row)*EMBED + kc*8 };

  floatx4 acc[3][4][2];
  #pragma unroll
  for (int z = 0; z < 3; ++z)
    #pragma unroll
    for (int mi = 0; mi < 4; ++mi)
      #pragma unroll
      for (int ni = 0; ni < 2; ++ni)
        acc[z][mi][ni] = (floatx4){0.f, 0.f, 0.f, 0.f};

  // prologue: stage kt=0 into buffer 0
  gl_lds16(A0,            As + tid*8);
  gl_lds16(A0 + 64*EMBED, As + (256 + tid)*8);
  #pragma unroll
  for (int z = 0; z < 3; ++z)
    gl_lds16(B0[z], Bs[z] + tid*8);

  for (int kt = 0; kt < EMBED/32; ++kt){
    const int cur = kt & 1;
    // one barrier per kt: drains vmcnt (buf[cur] DMA done) + all waves done
    // reading buf[cur^1] last iter -> safe to overwrite below.
    __syncthreads();
    if (kt + 1 < EMBED/32){
      const int k0 = (kt + 1) * 32;
      gl_lds16(A0 + k0,            As + (cur^1)*4096 + tid*8);
      gl_lds16(A0 + 64*EMBED + k0, As + (cur^1)*4096 + (256 + tid)*8);
      #pragma unroll
      for (int z = 0; z < 3; ++z)
        gl_lds16(B0[z] + k0, Bs[z] + (cur^1)*2048 + tid*8);
    }
    const u16* Ac = As + cur*4096;
    bf16x8 af[4];
    #pragma unroll
    for (int mi = 0; mi < 4; ++mi)
      af[mi] = ld_frag(&Ac[(wm + mi*16 + lm)*32 + quad*8]);
    #pragma unroll
    for (int z = 0; z < 3; ++z){
      const u16* Bc = Bs[z] + cur*2048;
      bf16x8 bfz[2];
      #pragma unroll
      for (int ni = 0; ni < 2; ++ni)
        bfz[ni] = ld_frag(&Bc[(wn + ni*16 + lm)*32 + quad*8]);
      #pragma unroll
      for (int mi = 0; mi < 4; ++mi)
        #pragma unroll
        for (int ni = 0; ni < 2; ++ni)
          acc[z][mi][ni] = mfma16(af[mi], bfz[ni], acc[z][mi][ni]);
    }
  }

  // ---- epilogues: direct stores ----
  // z=0 (Q, scaled) and z=1 (K): [bh][s][d]
  #pragma unroll
  for (int z = 0; z < 2; ++z){
    const float scale = (z == 0) ? QSCALE : 1.0f;
    u16* outz = QKV + (size_t)z * ZSTRIDE;
    #pragma unroll
    for (int mi = 0; mi < 4; ++mi)
      #pragma unroll
      for (int ni = 0; ni < 2; ++ni)
        #pragma unroll
        for (int r = 0; r < 4; ++r){
          int m = m0 + wm + mi*16 + quad*4 + r;
          int n = n0 + wn + ni*16 + lm;
          int b = m >> 11, s = m & 2047, h = n >> 6, d = n & 63;
          outz[(((size_t)(b*NH + h))*SEQ + s)*DKH + d] = f2bf(acc[z][mi][ni][r] * scale);
        }
  }
  // z=2 (V): [bh][d][s], 4 consecutive s per thread -> uint2 store
  {
    u16* outz = QKV + (size_t)2 * ZSTRIDE;
    #pragma unroll
    for (int mi = 0; mi < 4; ++mi)
      #pragma unroll
      for (int ni = 0; ni < 2; ++ni){
        int mbase = m0 + wm + mi*16 + quad*4;
        int n = n0 + wn + ni*16 + lm;
        int b = mbase >> 11, sb = mbase & 2047;
        int h = n >> 6, d = n & 63;
        u16* dst = outz + (((size_t)(b*NH + h))*DKH + d)*SEQ + sb;
        uint2 pv;
        pv.x = pk2(acc[2][mi][ni][0], acc[2][mi][ni][1]);
        pv.y = pk2(acc[2][mi][ni][2], acc[2][mi][ni][3]);
        *reinterpret_cast<uint2*>(dst) = pv;
      }
  }
}

// Final: out = Attn * Wo^T, fp32 out [b*s][e]. grid (64, 8): x = m-tile.
__global__ __launch_bounds__(256) void gemm_out(const u16* __restrict__ A,
    const u16* __restrict__ W, float* __restrict__ C){
  __shared__ __attribute__((aligned(16))) u16 As[2*128*32];
  __shared__ __attribute__((aligned(16))) u16 Bs[2*128*32];
  const int m0 = blockIdx.x * 128, n0 = blockIdx.y * 128;
  floatx4 acc[4][4];
  gemm_core_db(A + (size_t)m0*EMBED, W + (size_t)n0*EMBED, As, Bs, acc);

  const int tid = threadIdx.x, lane = tid & 63, w = tid >> 6;
  const int lm = lane & 15, quad = lane >> 4;
  const int wm = (w & 1) * 64, wn = (w >> 1) * 64;
  #pragma unroll
  for (int mi = 0; mi < 4; ++mi)
    #pragma unroll
    for (int ni = 0; ni < 4; ++ni)
      #pragma unroll
      for (int r = 0; r < 4; ++r){
        int m = m0 + wm + mi*16 + quad*4 + r;
        int n = n0 + wn + ni*16 + lm;
        C[(size_t)m*EMBED + n] = acc[mi][ni][r];
      }
}

// =================== fused attention (P stays in registers) ===================
// grid (64, 16): x = bh (XCD-local L2 reuse of K/V), y = q-block of 128 rows.
// 4 waves x 32 q (2 q-tiles). Keys chunked by 64, K/V double-buffered DMA,
// single barrier per kt. S^T C-layout (q=lm, key=quad*4+reg) == A-operand
// k-slot layout of mfma_f32_16x16x32_bf16 when TWO consecutive 16-key tiles
// pack into one bf16x8. PV + row-sum on full-width K=32 MFMAs. setprio kept
// (neutral-to-slightly-positive). V staged [d][key] stride 64, XOR swizzle
// at DMA source. LDS = 33 KB -> 4 blocks/CU.
#define KSS 520
__global__ __launch_bounds__(256, 4) void attn_kernel(const u16* __restrict__ QKV,
                                                      u16* __restrict__ Out){
  __shared__ __attribute__((aligned(16))) u16 Ks[2][8*KSS];   // 16.6 KB
  __shared__ __attribute__((aligned(16))) u16 Vs[2][64*64];   // 16.4 KB

  const int tid = threadIdx.x, lane = tid & 63, w = tid >> 6;
  const int lm = lane & 15, quad = lane >> 4;
  const int bh = blockIdx.x;
  const int q0 = blockIdx.y * 128;
  const u16* Qh = QKV + (size_t)bh * SEQ * DKH;
  const u16* Kh = QKV + ZSTRIDE + (size_t)bh * SEQ * DKH;
  const u16* Vh = QKV + 2*ZSTRIDE + (size_t)bh * DKH * SEQ;  // [d][s] plain

  const int sK = tid & 63, cK = tid >> 6;
  const int dV = tid >> 3, gV = tid & 7;
  const size_t vsrc0 = (size_t)dV * SEQ + ((gV ^ (dV & 7)) * 8);
  const size_t vsrc1 = vsrc0 + (size_t)32 * SEQ;

  bf16x8 qf[2][2];
  #pragma unroll
  for (int qt = 0; qt < 2; ++qt)
    #pragma unroll
    for (int st = 0; st < 2; ++st)
      qf[qt][st] = ld_frag(Qh + (size_t)(q0 + w*32 + qt*16 + lm)*DKH + st*32 + quad*8);

  const uint4 ONESW = {0x3F803F80u, 0x3F803F80u, 0x3F803F80u, 0x3F803F80u};
  const bf16x8 ones8 = __builtin_bit_cast(bf16x8, ONESW);    // bf16 1.0 x8

  floatx4 o[2][4], lac[2];
  #pragma unroll
  for (int qt = 0; qt < 2; ++qt){
    lac[qt] = (floatx4){0.f, 0.f, 0.f, 0.f};
    #pragma unroll
    for (int dt = 0; dt < 4; ++dt) o[qt][dt] = (floatx4){0.f, 0.f, 0.f, 0.f};
  }

  gl_lds16(Kh + (size_t)sK*DKH + cK*8,     Ks[0] + cK*KSS + sK*8);
  gl_lds16(Kh + (size_t)sK*DKH + (cK+4)*8, Ks[0] + (cK+4)*KSS + sK*8);
  gl_lds16(Vh + vsrc0,                     Vs[0] + tid*8);
  gl_lds16(Vh + vsrc1,                     Vs[0] + 2048 + tid*8);

  for (int kt = 0; kt < SEQ/64; ++kt){
    const int cur = kt & 1;
    __syncthreads();
    if (kt + 1 < SEQ/64){
      const int nk0 = (kt + 1) * 64;
      gl_lds16(Kh + (size_t)(nk0 + sK)*DKH + cK*8,     Ks[cur^1] + cK*KSS + sK*8);
      gl_lds16(Kh + (size_t)(nk0 + sK)*DKH + (cK+4)*8, Ks[cur^1] + (cK+4)*KSS + sK*8);
      gl_lds16(Vh + vsrc0 + nk0,                       Vs[cur^1] + tid*8);
      gl_lds16(Vh + vsrc1 + nk0,                       Vs[cur^1] + 2048 + tid*8);
    }
    const u16* Kc = Ks[cur];
    const u16* Vc = Vs[cur];

    #pragma unroll
    for (int u = 0; u < 2; ++u){           // pair of 16-key tiles = 32 keys
      uint2 ph[2][2];                      // [qt][half]: exp'd P, 4 bf16 each
      #pragma unroll
      for (int half = 0; half < 2; ++half){
        const int t = u*2 + half;
        bf16x8 kf0 = ld_frag(&Kc[quad*KSS     + (t*16 + lm)*8]);
        bf16x8 kf1 = ld_frag(&Kc[(quad+4)*KSS + (t*16 + lm)*8]);
        #pragma unroll
        for (int qt = 0; qt < 2; ++qt){
          floatx4 s = (floatx4){0.f,0.f,0.f,0.f};
          __builtin_amdgcn_s_setprio(1);
          s = mfma16(kf0, qf[qt][0], s);
          s = mfma16(kf1, qf[qt][1], s);
          __builtin_amdgcn_s_setprio(0);
          ph[qt][half].x = pk2(__builtin_amdgcn_exp2f(s[0]), __builtin_amdgcn_exp2f(s[1]));
          ph[qt][half].y = pk2(__builtin_amdgcn_exp2f(s[2]), __builtin_amdgcn_exp2f(s[3]));
        }
      }
      bf16x8 pf[2];
      #pragma unroll
      for (int qt = 0; qt < 2; ++qt){
        uint4 pp = {ph[qt][0].x, ph[qt][0].y, ph[qt][1].x, ph[qt][1].y};
        pf[qt] = __builtin_bit_cast(bf16x8, pp);
      }
      const int cg0 = (((u*4     + (quad >> 1)) ^ (lm & 7)) * 8) + (quad & 1) * 4;
      const int cg1 = (((u*4 + 2 + (quad >> 1)) ^ (lm & 7)) * 8) + (quad & 1) * 4;
      __builtin_amdgcn_s_setprio(1);
      lac[0] = mfma16(pf[0], ones8, lac[0]);
      lac[1] = mfma16(pf[1], ones8, lac[1]);
      #pragma unroll
      for (int dt = 0; dt < 4; ++dt){
        uint2 vlo = *(const uint2*)(Vc + (dt*16 + lm)*64 + cg0);
        uint2 vhi = *(const uint2*)(Vc + (dt*16 + lm)*64 + cg1);
        uint4 vv = {vlo.x, vlo.y, vhi.x, vhi.y};
        bf16x8 vb = __builtin_bit_cast(bf16x8, vv);
        o[0][dt] = mfma16(pf[0], vb, o[0][dt]);
        o[1][dt] = mfma16(pf[1], vb, o[1][dt]);
      }
      __builtin_amdgcn_s_setprio(0);
    }
  }

  const int bI = bh >> 4, h = bh & 15;
  #pragma unroll
  for (int qt = 0; qt < 2; ++qt){
    floatx4 inv;
    #pragma unroll
    for (int r = 0; r < 4; ++r) inv[r] = __builtin_amdgcn_rcpf(lac[qt][r]);
    #pragma unroll
    for (int dt = 0; dt < 4; ++dt)
      #pragma unroll
      for (int r = 0; r < 4; ++r){
        int s = q0 + w*32 + qt*16 + quad*4 + r;
        Out[((size_t)(bI*SEQ + s))*EMBED + h*DKH + dt*16 + lm] = f2bf(o[qt][dt][r] * inv[r]);
      }
  }
}

// =================== launch ===================
extern "C" void kernel_launch(void* const* d_in, const int* in_sizes, int n_in,
                              void* d_out, int out_size, void* d_ws, size_t ws_size,
                              hipStream_t stream){
  const float* x  = (const float*)d_in[0];
  const float* Wq = (const float*)d_in[1];
  const float* Wk = (const float*)d_in[2];
  const float* Wv = (const float*)d_in[3];
  const float* Wo = (const float*)d_in[4];
  float* out = (float*)d_out;

  char* ws = (char*)d_ws;
  u16* Xb  = (u16*)ws;                          // 16 MB
  u16* Wqb = (u16*)(ws + (size_t)16777216);     // 4 x 2 MB
  u16* Wkb = Wqb + 1048576;
  u16* Wvb = Wkb + 1048576;
  u16* Wob = Wvb + 1048576;
  u16* QKV = (u16*)(ws + (size_t)25165824);     // 3 x 16.78 MB
  u16* At  = (u16*)(ws + (size_t)75497472);     // 16 MB

  cvt_all<<<12288, 256, 0, stream>>>(x, Wq, Wk, Wv, Wo, Xb, Wqb, Wkb, Wvb, Wob);
  gemm_qkv<<<dim3(64, 16), 256, 0, stream>>>(Xb, Wqb, Wkb, Wvb, QKV);
  attn_kernel<<<dim3(64, 16), 256, 0, stream>>>(QKV, At);
  gemm_out<<<dim3(64, 8), 256, 0, stream>>>(At, Wob, out);
}

// Round 5
// 256.751 us; speedup vs baseline: 1.0624x; 1.0624x over previous
//
#include <hip/hip_runtime.h>
#include <hip/hip_bf16.h>

typedef unsigned short u16;
typedef unsigned int   u32;
typedef __attribute__((ext_vector_type(8))) __bf16 bf16x8;
typedef __attribute__((ext_vector_type(2))) __bf16 bf16x2;
typedef __attribute__((ext_vector_type(8))) u16    ushort8v;
typedef __attribute__((ext_vector_type(2))) float  f32x2;
typedef __attribute__((ext_vector_type(4))) float  floatx4;

#define EMBED 1024
#define SEQ   2048
#define BATCH 4
#define NH    16
#define DKH   64
#define BHN   (BATCH*NH)              // 64
#define ZSTRIDE ((size_t)BHN*SEQ*DKH) // elements per Q/K/V plane

// ---- fp32 -> bf16 RTNE ----
__device__ __forceinline__ u16 f2bf(float f){
  union { float f; unsigned u; } v; v.f = f;
  unsigned r = (v.u + 0x7FFFu + ((v.u >> 16) & 1u)) >> 16;
  return (u16)r;
}
// packed pair via v_cvt_pk_bf16_f32
__device__ __forceinline__ u32 pk2(float a, float b){
  f32x2 v = {a, b};
  return __builtin_bit_cast(u32, __builtin_convertvector(v, bf16x2));
}

__device__ __forceinline__ bf16x8 ld_frag(const u16* p){
  return __builtin_bit_cast(bf16x8, *(const ushort8v*)p);
}

__device__ __forceinline__ floatx4 mfma16(bf16x8 a, bf16x8 b, floatx4 c){
  return __builtin_amdgcn_mfma_f32_16x16x32_bf16(a, b, c, 0, 0, 0);
}

// async global->LDS, 16B per lane; LDS dst must be uniform_base + lane*16
__device__ __forceinline__ void gl_lds16(const u16* g, u16* l){
  __builtin_amdgcn_global_load_lds((const __attribute__((address_space(1))) void*)g,
                                   (__attribute__((address_space(3))) void*)l,
                                   16, 0, 0);
}
__device__ __forceinline__ void gl_lds16f(const float* g, float* l){
  __builtin_amdgcn_global_load_lds((const __attribute__((address_space(1))) void*)g,
                                   (__attribute__((address_space(3))) void*)l,
                                   16, 0, 0);
}

// =================== weights-only cast kernel (X cast folded into gemm_qkv) ===
__global__ __launch_bounds__(256) void cvt_w(
    const float* __restrict__ wq, const float* __restrict__ wk,
    const float* __restrict__ wv, const float* __restrict__ wo,
    u16* __restrict__ Wqb, u16* __restrict__ Wkb,
    u16* __restrict__ Wvb, u16* __restrict__ Wob){
  int b = blockIdx.x;
  int k = b >> 10, r = b & 1023;
  const float* src = (k==0) ? wq : (k==1) ? wk : (k==2) ? wv : wo;
  u16* dst = (k==0) ? Wqb : (k==1) ? Wkb : (k==2) ? Wvb : Wob;
  int i = r*256 + threadIdx.x;
  float4 v = ((const float4*)src)[i];
  ushort4 o;
  o.x = f2bf(v.x); o.y = f2bf(v.y); o.z = f2bf(v.z); o.w = f2bf(v.w);
  ((ushort4*)dst)[i] = o;
}

// ========== GEMM core (for gemm_out): double-buffered DMA, ONE barrier/kt ======
__device__ __forceinline__ void gemm_core_db(const u16* Abase, const u16* Bbase,
                                             u16* As, u16* Bs, floatx4 acc[4][4]){
  const int tid  = threadIdx.x;
  const int lane = tid & 63, w = tid >> 6;
  const int lm   = lane & 15, quad = lane >> 4;
  const int wm   = (w & 1) * 64, wn = (w >> 1) * 64;
  const int row0 = tid >> 2, kc = tid & 3;
  const int row1 = (256 + tid) >> 2;

  #pragma unroll
  for (int mi = 0; mi < 4; ++mi)
    #pragma unroll
    for (int ni = 0; ni < 4; ++ni)
      acc[mi][ni] = (floatx4){0.f, 0.f, 0.f, 0.f};

  gl_lds16(Abase + (size_t)row0*EMBED + kc*8, As + tid*8);
  gl_lds16(Bbase + (size_t)row0*EMBED + kc*8, Bs + tid*8);
  gl_lds16(Abase + (size_t)row1*EMBED + kc*8, As + (256 + tid)*8);
  gl_lds16(Bbase + (size_t)row1*EMBED + kc*8, Bs + (256 + tid)*8);

  for (int kt = 0; kt < EMBED/32; ++kt){
    const int cur = kt & 1;
    __syncthreads();
    if (kt + 1 < EMBED/32){
      const int k0 = (kt + 1) * 32;
      u16* Ad = As + (cur^1)*128*32;
      u16* Bd = Bs + (cur^1)*128*32;
      gl_lds16(Abase + (size_t)row0*EMBED + k0 + kc*8, Ad + tid*8);
      gl_lds16(Bbase + (size_t)row0*EMBED + k0 + kc*8, Bd + tid*8);
      gl_lds16(Abase + (size_t)row1*EMBED + k0 + kc*8, Ad + (256 + tid)*8);
      gl_lds16(Bbase + (size_t)row1*EMBED + k0 + kc*8, Bd + (256 + tid)*8);
    }
    const u16* Ac = As + cur*128*32;
    const u16* Bc = Bs + cur*128*32;
    bf16x8 af[4], bf[4];
    #pragma unroll
    for (int mi = 0; mi < 4; ++mi)
      af[mi] = ld_frag(&Ac[(wm + mi*16 + lm)*32 + quad*8]);
    #pragma unroll
    for (int ni = 0; ni < 4; ++ni)
      bf[ni] = ld_frag(&Bc[(wn + ni*16 + lm)*32 + quad*8]);
    #pragma unroll
    for (int mi = 0; mi < 4; ++mi)
      #pragma unroll
      for (int ni = 0; ni < 4; ++ni)
        acc[mi][ni] = mfma16(af[mi], bf[ni], acc[mi][ni]);
  }
}

// ============== fused QKV projection (R3-v1 structure + f32-X staging) =========
// grid (64, 8): x = m-tile (128 rows), y = n-tile (128 cols). Q,K,V share the
// A operand -> stage X ONCE per kt, 3 B tiles, 48 MFMA/wave/kt per barrier.
// R4 lesson: work-per-barrier dominates waves/SIMD at K=1024 — keep the big
// acc[3][4][4] tile (1 heavy wave/SIMD beats 3 light ones).
// NEW: A staged as RAW F32 from x (X-cast kernel eliminated for X). A-tile
// [128][32] f32, 16B units XOR-swizzled (uu ^= row&7) at the DMA *source*,
// read with the same XOR -> conflict-free b128 reads; cvt to bf16 via
// v_cvt_pk during frag load (hidden under 48 MFMA). LDS 80 KB -> 2 blocks/CU.
// z=0: Q (scaled), z=1: K — layout [bh][s][d]; z=2: V — layout [bh][d][s].
#define QSCALE 0.1803368801111204f   // 0.125 * log2(e)
__global__ __launch_bounds__(256, 2) void gemm_qkv(const float* __restrict__ X,
    const u16* __restrict__ Wq, const u16* __restrict__ Wk, const u16* __restrict__ Wv,
    u16* __restrict__ QKV){
  __shared__ __attribute__((aligned(16))) float Asf[2*128*32];   // 32 KB (f32)
  __shared__ __attribute__((aligned(16))) u16   Bs[3][2*128*32]; // 48 KB

  const int tid = threadIdx.x, lane = tid & 63, w = tid >> 6;
  const int lm = lane & 15, quad = lane >> 4;
  const int wm = (w & 1) * 64, wn = (w >> 1) * 64;
  const int m0 = blockIdx.x * 128, n0 = blockIdx.y * 128;
  const int rowB = tid >> 2, kcB = tid & 3;

  // A staging: unit U = r*256+tid -> row = r*32 + (tid>>3), uu = tid&7.
  // XOR swizzle at source: src 16B-unit = uu ^ (row&7); (row&7)=(tid>>3)&7
  // for all r (r*32 ≡ 0 mod 8) -> one offset for all 4 fills.
  const int arow = tid >> 3;
  const int aoff = ((tid & 7) ^ (arow & 7)) * 4;   // floats within 32-float row
  const float* A0 = X + (size_t)(m0 + arow)*EMBED + aoff;   // +r*32*EMBED rows

  const u16* B0[3] = {
    Wq + (size_t)(n0 + rowB)*EMBED + kcB*8,
    Wk + (size_t)(n0 + rowB)*EMBED + kcB*8,
    Wv + (size_t)(n0 + rowB)*EMBED + kcB*8 };

  floatx4 acc[3][4][4];
  #pragma unroll
  for (int z = 0; z < 3; ++z)
    #pragma unroll
    for (int mi = 0; mi < 4; ++mi)
      #pragma unroll
      for (int ni = 0; ni < 4; ++ni)
        acc[z][mi][ni] = (floatx4){0.f, 0.f, 0.f, 0.f};

  // prologue: stage kt=0 into buffer 0
  #pragma unroll
  for (int r = 0; r < 4; ++r)
    gl_lds16f(A0 + (size_t)r*32*EMBED, Asf + (r*256 + tid)*4);
  #pragma unroll
  for (int z = 0; z < 3; ++z){
    gl_lds16(B0[z],            Bs[z] + tid*8);
    gl_lds16(B0[z] + 64*EMBED, Bs[z] + (256 + tid)*8);
  }

  for (int kt = 0; kt < EMBED/32; ++kt){
    const int cur = kt & 1;
    // one barrier per kt: drains vmcnt (buf[cur] DMA done) + all waves done
    // reading buf[cur^1] last iter -> safe to overwrite below.
    __syncthreads();
    if (kt + 1 < EMBED/32){
      const int k0 = (kt + 1) * 32;
      #pragma unroll
      for (int r = 0; r < 4; ++r)
        gl_lds16f(A0 + (size_t)r*32*EMBED + k0, Asf + (cur^1)*4096 + (r*256 + tid)*4);
      #pragma unroll
      for (int z = 0; z < 3; ++z){
        gl_lds16(B0[z] + k0,            Bs[z] + (cur^1)*4096 + tid*8);
        gl_lds16(B0[z] + 64*EMBED + k0, Bs[z] + (cur^1)*4096 + (256 + tid)*8);
      }
    }
    const float* Acf = Asf + cur*4096;
    bf16x8 af[4];
    #pragma unroll
    for (int mi = 0; mi < 4; ++mi){
      const int R = wm + mi*16 + lm;                 // R&7 == lm&7
      const int u0 = (quad*2)     ^ (lm & 7);
      const int u1 = (quad*2 + 1) ^ (lm & 7);
      floatx4 a0 = *(const floatx4*)(Acf + R*32 + u0*4);
      floatx4 a1 = *(const floatx4*)(Acf + R*32 + u1*4);
      uint4 ap = { pk2(a0[0],a0[1]), pk2(a0[2],a0[3]),
                   pk2(a1[0],a1[1]), pk2(a1[2],a1[3]) };
      af[mi] = __builtin_bit_cast(bf16x8, ap);
    }
    #pragma unroll
    for (int z = 0; z < 3; ++z){
      const u16* Bc = Bs[z] + cur*4096;
      bf16x8 bfz[4];
      #pragma unroll
      for (int ni = 0; ni < 4; ++ni)
        bfz[ni] = ld_frag(&Bc[(wn + ni*16 + lm)*32 + quad*8]);
      #pragma unroll
      for (int mi = 0; mi < 4; ++mi)
        #pragma unroll
        for (int ni = 0; ni < 4; ++ni)
          acc[z][mi][ni] = mfma16(af[mi], bfz[ni], acc[z][mi][ni]);
    }
  }

  // ---- epilogues: direct stores ----
  // z=0 (Q, scaled) and z=1 (K): [bh][s][d]
  #pragma unroll
  for (int z = 0; z < 2; ++z){
    const float scale = (z == 0) ? QSCALE : 1.0f;
    u16* outz = QKV + (size_t)z * ZSTRIDE;
    #pragma unroll
    for (int mi = 0; mi < 4; ++mi)
      #pragma unroll
      for (int ni = 0; ni < 4; ++ni)
        #pragma unroll
        for (int r = 0; r < 4; ++r){
          int m = m0 + wm + mi*16 + quad*4 + r;
          int n = n0 + wn + ni*16 + lm;
          int b = m >> 11, s = m & 2047, h = n >> 6, d = n & 63;
          outz[(((size_t)(b*NH + h))*SEQ + s)*DKH + d] = f2bf(acc[z][mi][ni][r] * scale);
        }
  }
  // z=2 (V): [bh][d][s], 4 consecutive s per thread -> uint2 store
  {
    u16* outz = QKV + (size_t)2 * ZSTRIDE;
    #pragma unroll
    for (int mi = 0; mi < 4; ++mi)
      #pragma unroll
      for (int ni = 0; ni < 4; ++ni){
        int mbase = m0 + wm + mi*16 + quad*4;
        int n = n0 + wn + ni*16 + lm;
        int b = mbase >> 11, sb = mbase & 2047;
        int h = n >> 6, d = n & 63;
        u16* dst = outz + (((size_t)(b*NH + h))*DKH + d)*SEQ + sb;
        uint2 pv;
        pv.x = pk2(acc[2][mi][ni][0], acc[2][mi][ni][1]);
        pv.y = pk2(acc[2][mi][ni][2], acc[2][mi][ni][3]);
        *reinterpret_cast<uint2*>(dst) = pv;
      }
  }
}

// Final: out = Attn * Wo^T, fp32 out [b*s][e]. grid (64, 8): x = m-tile.
__global__ __launch_bounds__(256) void gemm_out(const u16* __restrict__ A,
    const u16* __restrict__ W, float* __restrict__ C){
  __shared__ __attribute__((aligned(16))) u16 As[2*128*32];
  __shared__ __attribute__((aligned(16))) u16 Bs[2*128*32];
  const int m0 = blockIdx.x * 128, n0 = blockIdx.y * 128;
  floatx4 acc[4][4];
  gemm_core_db(A + (size_t)m0*EMBED, W + (size_t)n0*EMBED, As, Bs, acc);

  const int tid = threadIdx.x, lane = tid & 63, w = tid >> 6;
  const int lm = lane & 15, quad = lane >> 4;
  const int wm = (w & 1) * 64, wn = (w >> 1) * 64;
  #pragma unroll
  for (int mi = 0; mi < 4; ++mi)
    #pragma unroll
    for (int ni = 0; ni < 4; ++ni)
      #pragma unroll
      for (int r = 0; r < 4; ++r){
        int m = m0 + wm + mi*16 + quad*4 + r;
        int n = n0 + wn + ni*16 + lm;
        C[(size_t)m*EMBED + n] = acc[mi][ni][r];
      }
}

// =================== fused attention (P stays in registers) ===================
// grid (64, 16): x = bh (XCD-local L2 reuse of K/V), y = q-block of 128 rows.
// 4 waves x 32 q (2 q-tiles). Keys chunked by 64, K/V double-buffered DMA,
// single barrier per kt. S^T C-layout (q=lm, key=quad*4+reg) == A-operand
// k-slot layout of mfma_f32_16x16x32_bf16 when TWO consecutive 16-key tiles
// pack into one bf16x8. PV + row-sum on full-width K=32 MFMAs. setprio kept
// (neutral-to-slightly-positive). V staged [d][key] stride 64, XOR swizzle
// at DMA source. LDS = 33 KB -> 4 blocks/CU.
#define KSS 520
__global__ __launch_bounds__(256, 4) void attn_kernel(const u16* __restrict__ QKV,
                                                      u16* __restrict__ Out){
  __shared__ __attribute__((aligned(16))) u16 Ks[2][8*KSS];   // 16.6 KB
  __shared__ __attribute__((aligned(16))) u16 Vs[2][64*64];   // 16.4 KB

  const int tid = threadIdx.x, lane = tid & 63, w = tid >> 6;
  const int lm = lane & 15, quad = lane >> 4;
  const int bh = blockIdx.x;
  const int q0 = blockIdx.y * 128;
  const u16* Qh = QKV + (size_t)bh * SEQ * DKH;
  const u16* Kh = QKV + ZSTRIDE + (size_t)bh * SEQ * DKH;
  const u16* Vh = QKV + 2*ZSTRIDE + (size_t)bh * DKH * SEQ;  // [d][s] plain

  const int sK = tid & 63, cK = tid >> 6;
  const int dV = tid >> 3, gV = tid & 7;
  const size_t vsrc0 = (size_t)dV * SEQ + ((gV ^ (dV & 7)) * 8);
  const size_t vsrc1 = vsrc0 + (size_t)32 * SEQ;

  bf16x8 qf[2][2];
  #pragma unroll
  for (int qt = 0; qt < 2; ++qt)
    #pragma unroll
    for (int st = 0; st < 2; ++st)
      qf[qt][st] = ld_frag(Qh + (size_t)(q0 + w*32 + qt*16 + lm)*DKH + st*32 + quad*8);

  const uint4 ONESW = {0x3F803F80u, 0x3F803F80u, 0x3F803F80u, 0x3F803F80u};
  const bf16x8 ones8 = __builtin_bit_cast(bf16x8, ONESW);    // bf16 1.0 x8

  floatx4 o[2][4], lac[2];
  #pragma unroll
  for (int qt = 0; qt < 2; ++qt){
    lac[qt] = (floatx4){0.f, 0.f, 0.f, 0.f};
    #pragma unroll
    for (int dt = 0; dt < 4; ++dt) o[qt][dt] = (floatx4){0.f, 0.f, 0.f, 0.f};
  }

  gl_lds16(Kh + (size_t)sK*DKH + cK*8,     Ks[0] + cK*KSS + sK*8);
  gl_lds16(Kh + (size_t)sK*DKH + (cK+4)*8, Ks[0] + (cK+4)*KSS + sK*8);
  gl_lds16(Vh + vsrc0,                     Vs[0] + tid*8);
  gl_lds16(Vh + vsrc1,                     Vs[0] + 2048 + tid*8);

  for (int kt = 0; kt < SEQ/64; ++kt){
    const int cur = kt & 1;
    __syncthreads();
    if (kt + 1 < SEQ/64){
      const int nk0 = (kt + 1) * 64;
      gl_lds16(Kh + (size_t)(nk0 + sK)*DKH + cK*8,     Ks[cur^1] + cK*KSS + sK*8);
      gl_lds16(Kh + (size_t)(nk0 + sK)*DKH + (cK+4)*8, Ks[cur^1] + (cK+4)*KSS + sK*8);
      gl_lds16(Vh + vsrc0 + nk0,                       Vs[cur^1] + tid*8);
      gl_lds16(Vh + vsrc1 + nk0,                       Vs[cur^1] + 2048 + tid*8);
    }
    const u16* Kc = Ks[cur];
    const u16* Vc = Vs[cur];

    #pragma unroll
    for (int u = 0; u < 2; ++u){           // pair of 16-key tiles = 32 keys
      uint2 ph[2][2];                      // [qt][half]: exp'd P, 4 bf16 each
      #pragma unroll
      for (int half = 0; half < 2; ++half){
        const int t = u*2 + half;
        bf16x8 kf0 = ld_frag(&Kc[quad*KSS     + (t*16 + lm)*8]);
        bf16x8 kf1 = ld_frag(&Kc[(quad+4)*KSS + (t*16 + lm)*8]);
        #pragma unroll
        for (int qt = 0; qt < 2; ++qt){
          floatx4 s = (floatx4){0.f,0.f,0.f,0.f};
          __builtin_amdgcn_s_setprio(1);
          s = mfma16(kf0, qf[qt][0], s);
          s = mfma16(kf1, qf[qt][1], s);
          __builtin_amdgcn_s_setprio(0);
          ph[qt][half].x = pk2(__builtin_amdgcn_exp2f(s[0]), __builtin_amdgcn_exp2f(s[1]));
          ph[qt][half].y = pk2(__builtin_amdgcn_exp2f(s[2]), __builtin_amdgcn_exp2f(s[3]));
        }
      }
      bf16x8 pf[2];
      #pragma unroll
      for (int qt = 0; qt < 2; ++qt){
        uint4 pp = {ph[qt][0].x, ph[qt][0].y, ph[qt][1].x, ph[qt][1].y};
        pf[qt] = __builtin_bit_cast(bf16x8, pp);
      }
      const int cg0 = (((u*4     + (quad >> 1)) ^ (lm & 7)) * 8) + (quad & 1) * 4;
      const int cg1 = (((u*4 + 2 + (quad >> 1)) ^ (lm & 7)) * 8) + (quad & 1) * 4;
      __builtin_amdgcn_s_setprio(1);
      lac[0] = mfma16(pf[0], ones8, lac[0]);
      lac[1] = mfma16(pf[1], ones8, lac[1]);
      #pragma unroll
      for (int dt = 0; dt < 4; ++dt){
        uint2 vlo = *(const uint2*)(Vc + (dt*16 + lm)*64 + cg0);
        uint2 vhi = *(const uint2*)(Vc + (dt*16 + lm)*64 + cg1);
        uint4 vv = {vlo.x, vlo.y, vhi.x, vhi.y};
        bf16x8 vb = __builtin_bit_cast(bf16x8, vv);
        o[0][dt] = mfma16(pf[0], vb, o[0][dt]);
        o[1][dt] = mfma16(pf[1], vb, o[1][dt]);
      }
      __builtin_amdgcn_s_setprio(0);
    }
  }

  const int bI = bh >> 4, h = bh & 15;
  #pragma unroll
  for (int qt = 0; qt < 2; ++qt){
    floatx4 inv;
    #pragma unroll
    for (int r = 0; r < 4; ++r) inv[r] = __builtin_amdgcn_rcpf(lac[qt][r]);
    #pragma unroll
    for (int dt = 0; dt < 4; ++dt)
      #pragma unroll
      for (int r = 0; r < 4; ++r){
        int s = q0 + w*32 + qt*16 + quad*4 + r;
        Out[((size_t)(bI*SEQ + s))*EMBED + h*DKH + dt*16 + lm] = f2bf(o[qt][dt][r] * inv[r]);
      }
  }
}

// =================== launch ===================
extern "C" void kernel_launch(void* const* d_in, const int* in_sizes, int n_in,
                              void* d_out, int out_size, void* d_ws, size_t ws_size,
                              hipStream_t stream){
  const float* x  = (const float*)d_in[0];
  const float* Wq = (const float*)d_in[1];
  const float* Wk = (const float*)d_in[2];
  const float* Wv = (const float*)d_in[3];
  const float* Wo = (const float*)d_in[4];
  float* out = (float*)d_out;

  char* ws = (char*)d_ws;
  u16* Wqb = (u16*)(ws + (size_t)16777216);     // 4 x 2 MB (first 16 MB unused)
  u16* Wkb = Wqb + 1048576;
  u16* Wvb = Wkb + 1048576;
  u16* Wob = Wvb + 1048576;
  u16* QKV = (u16*)(ws + (size_t)25165824);     // 3 x 16.78 MB
  u16* At  = (u16*)(ws + (size_t)75497472);     // 16 MB

  cvt_w<<<4096, 256, 0, stream>>>(Wq, Wk, Wv, Wo, Wqb, Wkb, Wvb, Wob);
  gemm_qkv<<<dim3(64, 8), 256, 0, stream>>>(x, Wqb, Wkb, Wvb, QKV);
  attn_kernel<<<dim3(64, 16), 256, 0, stream>>>(QKV, At);
  gemm_out<<<dim3(64, 8), 256, 0, stream>>>(At, Wob, out);
}

// Round 6
// 250.816 us; speedup vs baseline: 1.0875x; 1.0237x over previous
//
#include <hip/hip_runtime.h>
#include <hip/hip_bf16.h>

typedef unsigned short u16;
typedef unsigned int   u32;
typedef __attribute__((ext_vector_type(8))) __bf16 bf16x8;
typedef __attribute__((ext_vector_type(2))) __bf16 bf16x2;
typedef __attribute__((ext_vector_type(8))) u16    ushort8v;
typedef __attribute__((ext_vector_type(2))) float  f32x2;
typedef __attribute__((ext_vector_type(4))) float  floatx4;

#define EMBED 1024
#define SEQ   2048
#define BATCH 4
#define NH    16
#define DKH   64
#define BHN   (BATCH*NH)              // 64
#define ZSTRIDE ((size_t)BHN*SEQ*DKH) // elements per Q/K/V plane

// ---- fp32 -> bf16 RTNE ----
__device__ __forceinline__ u16 f2bf(float f){
  union { float f; unsigned u; } v; v.f = f;
  unsigned r = (v.u + 0x7FFFu + ((v.u >> 16) & 1u)) >> 16;
  return (u16)r;
}
// packed pair via v_cvt_pk_bf16_f32
__device__ __forceinline__ u32 pk2(float a, float b){
  f32x2 v = {a, b};
  return __builtin_bit_cast(u32, __builtin_convertvector(v, bf16x2));
}

__device__ __forceinline__ bf16x8 ld_frag(const u16* p){
  return __builtin_bit_cast(bf16x8, *(const ushort8v*)p);
}

__device__ __forceinline__ floatx4 mfma16(bf16x8 a, bf16x8 b, floatx4 c){
  return __builtin_amdgcn_mfma_f32_16x16x32_bf16(a, b, c, 0, 0, 0);
}

// async global->LDS, 16B per lane; LDS dst must be uniform_base + lane*16
__device__ __forceinline__ void gl_lds16(const u16* g, u16* l){
  __builtin_amdgcn_global_load_lds((const __attribute__((address_space(1))) void*)g,
                                   (__attribute__((address_space(3))) void*)l,
                                   16, 0, 0);
}

// =================== fused cast kernel ===================
__global__ __launch_bounds__(256) void cvt_all(const float* __restrict__ x,
    const float* __restrict__ wq, const float* __restrict__ wk,
    const float* __restrict__ wv, const float* __restrict__ wo,
    u16* __restrict__ Xb, u16* __restrict__ Wqb, u16* __restrict__ Wkb,
    u16* __restrict__ Wvb, u16* __restrict__ Wob){
  int b = blockIdx.x;
  const float* src; u16* dst; int i;
  if (b < 8192){ src = x; dst = Xb; i = b*256 + threadIdx.x; }
  else {
    int k = (b - 8192) >> 10, r = (b - 8192) & 1023;
    src = (k==0) ? wq : (k==1) ? wk : (k==2) ? wv : wo;
    dst = (k==0) ? Wqb : (k==1) ? Wkb : (k==2) ? Wvb : Wob;
    i = r*256 + threadIdx.x;
  }
  float4 v = ((const float4*)src)[i];
  ushort4 o;
  o.x = f2bf(v.x); o.y = f2bf(v.y); o.z = f2bf(v.z); o.w = f2bf(v.w);
  ((ushort4*)dst)[i] = o;
}

// ============== fused QKV projection (R3-v1, measured 68 us) ===================
// grid (64, 8): x = m-tile (128 rows), y = n-tile (128 cols). Q,K,V share the
// A operand -> stage X ONCE per kt, 3 B tiles, 48 MFMA/wave/kt per barrier.
// R4 lesson: work-per-barrier dominates waves/SIMD at K=1024 — keep the big
// acc[3][4][4] tile. R5 lesson: f32-X staging fold regressed (+12 us) — the
// 48-MFMA phase has no VALU slack for in-loop cvt; bf16 A via cvt_all wins.
// LDS = 64 KB -> 2 blocks/CU, 512 blocks = full residency, zero tail.
// z=0: Q (scaled), z=1: K — layout [bh][s][d]; z=2: V — layout [bh][d][s].
#define QSCALE 0.1803368801111204f   // 0.125 * log2(e)
__global__ __launch_bounds__(256, 2) void gemm_qkv(const u16* __restrict__ X,
    const u16* __restrict__ Wq, const u16* __restrict__ Wk, const u16* __restrict__ Wv,
    u16* __restrict__ QKV){
  __shared__ __attribute__((aligned(16))) u16 As[2*128*32];      // 16 KB
  __shared__ __attribute__((aligned(16))) u16 Bs[3][2*128*32];   // 48 KB

  const int tid = threadIdx.x, lane = tid & 63, w = tid >> 6;
  const int lm = lane & 15, quad = lane >> 4;
  const int wm = (w & 1) * 64, wn = (w >> 1) * 64;
  const int m0 = blockIdx.x * 128, n0 = blockIdx.y * 128;
  const int row0 = tid >> 2, kc = tid & 3;

  const u16* A0 = X  + (size_t)(m0 + row0)*EMBED + kc*8;   // +64*EMBED for r=1
  const u16* B0[3] = {
    Wq + (size_t)(n0 + row0)*EMBED + kc*8,
    Wk + (size_t)(n0 + row0)*EMBED + kc*8,
    Wv + (size_t)(n0 + row0)*EMBED + kc*8 };

  floatx4 acc[3][4][4];
  #pragma unroll
  for (int z = 0; z < 3; ++z)
    #pragma unroll
    for (int mi = 0; mi < 4; ++mi)
      #pragma unroll
      for (int ni = 0; ni < 4; ++ni)
        acc[z][mi][ni] = (floatx4){0.f, 0.f, 0.f, 0.f};

  // prologue: stage kt=0 into buffer 0
  gl_lds16(A0,            As + tid*8);
  gl_lds16(A0 + 64*EMBED, As + (256 + tid)*8);
  #pragma unroll
  for (int z = 0; z < 3; ++z){
    gl_lds16(B0[z],            Bs[z] + tid*8);
    gl_lds16(B0[z] + 64*EMBED, Bs[z] + (256 + tid)*8);
  }

  for (int kt = 0; kt < EMBED/32; ++kt){
    const int cur = kt & 1;
    // one barrier per kt: drains vmcnt (buf[cur] DMA done) + all waves done
    // reading buf[cur^1] last iter -> safe to overwrite below.
    __syncthreads();
    if (kt + 1 < EMBED/32){
      const int k0 = (kt + 1) * 32;
      gl_lds16(A0 + k0,            As + (cur^1)*4096 + tid*8);
      gl_lds16(A0 + 64*EMBED + k0, As + (cur^1)*4096 + (256 + tid)*8);
      #pragma unroll
      for (int z = 0; z < 3; ++z){
        gl_lds16(B0[z] + k0,            Bs[z] + (cur^1)*4096 + tid*8);
        gl_lds16(B0[z] + 64*EMBED + k0, Bs[z] + (cur^1)*4096 + (256 + tid)*8);
      }
    }
    const u16* Ac = As + cur*4096;
    bf16x8 af[4];
    #pragma unroll
    for (int mi = 0; mi < 4; ++mi)
      af[mi] = ld_frag(&Ac[(wm + mi*16 + lm)*32 + quad*8]);
    #pragma unroll
    for (int z = 0; z < 3; ++z){
      const u16* Bc = Bs[z] + cur*4096;
      bf16x8 bfz[4];
      #pragma unroll
      for (int ni = 0; ni < 4; ++ni)
        bfz[ni] = ld_frag(&Bc[(wn + ni*16 + lm)*32 + quad*8]);
      #pragma unroll
      for (int mi = 0; mi < 4; ++mi)
        #pragma unroll
        for (int ni = 0; ni < 4; ++ni)
          acc[z][mi][ni] = mfma16(af[mi], bfz[ni], acc[z][mi][ni]);
    }
  }

  // ---- epilogues: direct stores ----
  // z=0 (Q, scaled) and z=1 (K): [bh][s][d]
  #pragma unroll
  for (int z = 0; z < 2; ++z){
    const float scale = (z == 0) ? QSCALE : 1.0f;
    u16* outz = QKV + (size_t)z * ZSTRIDE;
    #pragma unroll
    for (int mi = 0; mi < 4; ++mi)
      #pragma unroll
      for (int ni = 0; ni < 4; ++ni)
        #pragma unroll
        for (int r = 0; r < 4; ++r){
          int m = m0 + wm + mi*16 + quad*4 + r;
          int n = n0 + wn + ni*16 + lm;
          int b = m >> 11, s = m & 2047, h = n >> 6, d = n & 63;
          outz[(((size_t)(b*NH + h))*SEQ + s)*DKH + d] = f2bf(acc[z][mi][ni][r] * scale);
        }
  }
  // z=2 (V): [bh][d][s], 4 consecutive s per thread -> uint2 store
  {
    u16* outz = QKV + (size_t)2 * ZSTRIDE;
    #pragma unroll
    for (int mi = 0; mi < 4; ++mi)
      #pragma unroll
      for (int ni = 0; ni < 4; ++ni){
        int mbase = m0 + wm + mi*16 + quad*4;
        int n = n0 + wn + ni*16 + lm;
        int b = mbase >> 11, sb = mbase & 2047;
        int h = n >> 6, d = n & 63;
        u16* dst = outz + (((size_t)(b*NH + h))*DKH + d)*SEQ + sb;
        uint2 pv;
        pv.x = pk2(acc[2][mi][ni][0], acc[2][mi][ni][1]);
        pv.y = pk2(acc[2][mi][ni][2], acc[2][mi][ni][3]);
        *reinterpret_cast<uint2*>(dst) = pv;
      }
  }
}

// Final: out = Attn * Wo^T, fp32 out [b*s][e]. grid (64, 8): x = m-tile.
// BK=64: 32 MFMA per barrier, 16 kt (half the barrier/DMA-burst events of
// BK=32). Grid 512 = 2 blocks/CU (grid-limited), so the 64 KB LDS costs no
// occupancy. [128][64] rows would put all 16 lm-lanes of a frag read on the
// same 16-bank half -> source-side XOR swizzle (unit ^= row&7 at the DMA
// source, same XOR on read — the proven attn-V pattern) restores the even
// 8-dwords/bank distribution.
__global__ __launch_bounds__(256) void gemm_out(const u16* __restrict__ A,
    const u16* __restrict__ W, float* __restrict__ C){
  __shared__ __attribute__((aligned(16))) u16 As[2*128*64];   // 32 KB
  __shared__ __attribute__((aligned(16))) u16 Bs[2*128*64];   // 32 KB
  const int tid = threadIdx.x, lane = tid & 63, w = tid >> 6;
  const int lm = lane & 15, quad = lane >> 4;
  const int wm = (w & 1) * 64, wn = (w >> 1) * 64;
  const int m0 = blockIdx.x * 128, n0 = blockIdx.y * 128;

  // staging: tile = [128 rows][8 units of 16B]; unit i = j*256+tid ->
  // row = i>>3, c = i&7; source-swizzled global unit u' = c ^ (row&7).
  // row&7 = (tid>>3)&7 for all j (j*32 ≡ 0 mod 8) -> per-thread constant.
  const int srow = tid >> 3;
  const int ssw  = ((tid & 7) ^ (srow & 7)) * 8;   // u16 col offset
  const u16* Ab = A + (size_t)(m0 + srow)*EMBED + ssw;
  const u16* Bb = W + (size_t)(n0 + srow)*EMBED + ssw;

  floatx4 acc[4][4];
  #pragma unroll
  for (int mi = 0; mi < 4; ++mi)
    #pragma unroll
    for (int ni = 0; ni < 4; ++ni)
      acc[mi][ni] = (floatx4){0.f, 0.f, 0.f, 0.f};

  // prologue: stage kt=0 into buffer 0
  #pragma unroll
  for (int j = 0; j < 4; ++j){
    gl_lds16(Ab + (size_t)j*32*EMBED, As + (j*256 + tid)*8);
    gl_lds16(Bb + (size_t)j*32*EMBED, Bs + (j*256 + tid)*8);
  }

  for (int kt = 0; kt < EMBED/64; ++kt){
    const int cur = kt & 1;
    __syncthreads();
    if (kt + 1 < EMBED/64){
      const int k0 = (kt + 1) * 64;
      #pragma unroll
      for (int j = 0; j < 4; ++j){
        gl_lds16(Ab + (size_t)j*32*EMBED + k0, As + (cur^1)*8192 + (j*256 + tid)*8);
        gl_lds16(Bb + (size_t)j*32*EMBED + k0, Bs + (cur^1)*8192 + (j*256 + tid)*8);
      }
    }
    const u16* Ac = As + cur*8192;
    const u16* Bc = Bs + cur*8192;
    #pragma unroll
    for (int kh = 0; kh < 2; ++kh){
      // logical unit U = kh*4+quad; LDS unit = U ^ (row&7), row&7 == lm&7
      const int us = ((kh*4 + quad) ^ (lm & 7)) * 8;
      bf16x8 af[4], bf[4];
      #pragma unroll
      for (int mi = 0; mi < 4; ++mi)
        af[mi] = ld_frag(&Ac[(wm + mi*16 + lm)*64 + us]);
      #pragma unroll
      for (int ni = 0; ni < 4; ++ni)
        bf[ni] = ld_frag(&Bc[(wn + ni*16 + lm)*64 + us]);
      #pragma unroll
      for (int mi = 0; mi < 4; ++mi)
        #pragma unroll
        for (int ni = 0; ni < 4; ++ni)
          acc[mi][ni] = mfma16(af[mi], bf[ni], acc[mi][ni]);
    }
  }

  #pragma unroll
  for (int mi = 0; mi < 4; ++mi)
    #pragma unroll
    for (int ni = 0; ni < 4; ++ni)
      #pragma unroll
      for (int r = 0; r < 4; ++r){
        int m = m0 + wm + mi*16 + quad*4 + r;
        int n = n0 + wn + ni*16 + lm;
        C[(size_t)m*EMBED + n] = acc[mi][ni][r];
      }
}

// =================== fused attention (P stays in registers) ===================
// grid (64, 16): x = bh (XCD-local L2 reuse of K/V), y = q-block of 128 rows.
// 4 waves x 32 q (2 q-tiles). Keys chunked by 64, K/V double-buffered DMA,
// single barrier per kt. S^T C-layout (q=lm, key=quad*4+reg) == A-operand
// k-slot layout of mfma_f32_16x16x32_bf16 when TWO consecutive 16-key tiles
// pack into one bf16x8. PV + row-sum on full-width K=32 MFMAs. setprio kept
// (neutral-to-slightly-positive). V staged [d][key] stride 64, XOR swizzle
// at DMA source. LDS = 33 KB -> 4 blocks/CU.
#define KSS 520
__global__ __launch_bounds__(256, 4) void attn_kernel(const u16* __restrict__ QKV,
                                                      u16* __restrict__ Out){
  __shared__ __attribute__((aligned(16))) u16 Ks[2][8*KSS];   // 16.6 KB
  __shared__ __attribute__((aligned(16))) u16 Vs[2][64*64];   // 16.4 KB

  const int tid = threadIdx.x, lane = tid & 63, w = tid >> 6;
  const int lm = lane & 15, quad = lane >> 4;
  const int bh = blockIdx.x;
  const int q0 = blockIdx.y * 128;
  const u16* Qh = QKV + (size_t)bh * SEQ * DKH;
  const u16* Kh = QKV + ZSTRIDE + (size_t)bh * SEQ * DKH;
  const u16* Vh = QKV + 2*ZSTRIDE + (size_t)bh * DKH * SEQ;  // [d][s] plain

  const int sK = tid & 63, cK = tid >> 6;
  const int dV = tid >> 3, gV = tid & 7;
  const size_t vsrc0 = (size_t)dV * SEQ + ((gV ^ (dV & 7)) * 8);
  const size_t vsrc1 = vsrc0 + (size_t)32 * SEQ;

  bf16x8 qf[2][2];
  #pragma unroll
  for (int qt = 0; qt < 2; ++qt)
    #pragma unroll
    for (int st = 0; st < 2; ++st)
      qf[qt][st] = ld_frag(Qh + (size_t)(q0 + w*32 + qt*16 + lm)*DKH + st*32 + quad*8);

  const uint4 ONESW = {0x3F803F80u, 0x3F803F80u, 0x3F803F80u, 0x3F803F80u};
  const bf16x8 ones8 = __builtin_bit_cast(bf16x8, ONESW);    // bf16 1.0 x8

  floatx4 o[2][4], lac[2];
  #pragma unroll
  for (int qt = 0; qt < 2; ++qt){
    lac[qt] = (floatx4){0.f, 0.f, 0.f, 0.f};
    #pragma unroll
    for (int dt = 0; dt < 4; ++dt) o[qt][dt] = (floatx4){0.f, 0.f, 0.f, 0.f};
  }

  gl_lds16(Kh + (size_t)sK*DKH + cK*8,     Ks[0] + cK*KSS + sK*8);
  gl_lds16(Kh + (size_t)sK*DKH + (cK+4)*8, Ks[0] + (cK+4)*KSS + sK*8);
  gl_lds16(Vh + vsrc0,                     Vs[0] + tid*8);
  gl_lds16(Vh + vsrc1,                     Vs[0] + 2048 + tid*8);

  for (int kt = 0; kt < SEQ/64; ++kt){
    const int cur = kt & 1;
    __syncthreads();
    if (kt + 1 < SEQ/64){
      const int nk0 = (kt + 1) * 64;
      gl_lds16(Kh + (size_t)(nk0 + sK)*DKH + cK*8,     Ks[cur^1] + cK*KSS + sK*8);
      gl_lds16(Kh + (size_t)(nk0 + sK)*DKH + (cK+4)*8, Ks[cur^1] + (cK+4)*KSS + sK*8);
      gl_lds16(Vh + vsrc0 + nk0,                       Vs[cur^1] + tid*8);
      gl_lds16(Vh + vsrc1 + nk0,                       Vs[cur^1] + 2048 + tid*8);
    }
    const u16* Kc = Ks[cur];
    const u16* Vc = Vs[cur];

    #pragma unroll
    for (int u = 0; u < 2; ++u){           // pair of 16-key tiles = 32 keys
      uint2 ph[2][2];                      // [qt][half]: exp'd P, 4 bf16 each
      #pragma unroll
      for (int half = 0; half < 2; ++half){
        const int t = u*2 + half;
        bf16x8 kf0 = ld_frag(&Kc[quad*KSS     + (t*16 + lm)*8]);
        bf16x8 kf1 = ld_frag(&Kc[(quad+4)*KSS + (t*16 + lm)*8]);
        #pragma unroll
        for (int qt = 0; qt < 2; ++qt){
          floatx4 s = (floatx4){0.f,0.f,0.f,0.f};
          __builtin_amdgcn_s_setprio(1);
          s = mfma16(kf0, qf[qt][0], s);
          s = mfma16(kf1, qf[qt][1], s);
          __builtin_amdgcn_s_setprio(0);
          ph[qt][half].x = pk2(__builtin_amdgcn_exp2f(s[0]), __builtin_amdgcn_exp2f(s[1]));
          ph[qt][half].y = pk2(__builtin_amdgcn_exp2f(s[2]), __builtin_amdgcn_exp2f(s[3]));
        }
      }
      bf16x8 pf[2];
      #pragma unroll
      for (int qt = 0; qt < 2; ++qt){
        uint4 pp = {ph[qt][0].x, ph[qt][0].y, ph[qt][1].x, ph[qt][1].y};
        pf[qt] = __builtin_bit_cast(bf16x8, pp);
      }
      const int cg0 = (((u*4     + (quad >> 1)) ^ (lm & 7)) * 8) + (quad & 1) * 4;
      const int cg1 = (((u*4 + 2 + (quad >> 1)) ^ (lm & 7)) * 8) + (quad & 1) * 4;
      __builtin_amdgcn_s_setprio(1);
      lac[0] = mfma16(pf[0], ones8, lac[0]);
      lac[1] = mfma16(pf[1], ones8, lac[1]);
      #pragma unroll
      for (int dt = 0; dt < 4; ++dt){
        uint2 vlo = *(const uint2*)(Vc + (dt*16 + lm)*64 + cg0);
        uint2 vhi = *(const uint2*)(Vc + (dt*16 + lm)*64 + cg1);
        uint4 vv = {vlo.x, vlo.y, vhi.x, vhi.y};
        bf16x8 vb = __builtin_bit_cast(bf16x8, vv);
        o[0][dt] = mfma16(pf[0], vb, o[0][dt]);
        o[1][dt] = mfma16(pf[1], vb, o[1][dt]);
      }
      __builtin_amdgcn_s_setprio(0);
    }
  }

  const int bI = bh >> 4, h = bh & 15;
  #pragma unroll
  for (int qt = 0; qt < 2; ++qt){
    floatx4 inv;
    #pragma unroll
    for (int r = 0; r < 4; ++r) inv[r] = __builtin_amdgcn_rcpf(lac[qt][r]);
    #pragma unroll
    for (int dt = 0; dt < 4; ++dt)
      #pragma unroll
      for (int r = 0; r < 4; ++r){
        int s = q0 + w*32 + qt*16 + quad*4 + r;
        Out[((size_t)(bI*SEQ + s))*EMBED + h*DKH + dt*16 + lm] = f2bf(o[qt][dt][r] * inv[r]);
      }
  }
}

// =================== launch ===================
extern "C" void kernel_launch(void* const* d_in, const int* in_sizes, int n_in,
                              void* d_out, int out_size, void* d_ws, size_t ws_size,
                              hipStream_t stream){
  const float* x  = (const float*)d_in[0];
  const float* Wq = (const float*)d_in[1];
  const float* Wk = (const float*)d_in[2];
  const float* Wv = (const float*)d_in[3];
  const float* Wo = (const float*)d_in[4];
  float* out = (float*)d_out;

  char* ws = (char*)d_ws;
  u16* Xb  = (u16*)ws;                          // 16 MB
  u16* Wqb = (u16*)(ws + (size_t)16777216);     // 4 x 2 MB
  u16* Wkb = Wqb + 1048576;
  u16* Wvb = Wkb + 1048576;
  u16* Wob = Wvb + 1048576;
  u16* QKV = (u16*)(ws + (size_t)25165824);     // 3 x 16.78 MB
  u16* At  = (u16*)(ws + (size_t)75497472);     // 16 MB

  cvt_all<<<12288, 256, 0, stream>>>(x, Wq, Wk, Wv, Wo, Xb, Wqb, Wkb, Wvb, Wob);
  gemm_qkv<<<dim3(64, 8), 256, 0, stream>>>(Xb, Wqb, Wkb, Wvb, QKV);
  attn_kernel<<<dim3(64, 16), 256, 0, stream>>>(QKV, At);
  gemm_out<<<dim3(64, 8), 256, 0, stream>>>(At, Wob, out);
}